// Round 16
// baseline (297.678 us; speedup 1.0000x reference)
//
#include <hip/hip_runtime.h>
#include <hip/hip_bf16.h>
#include <math.h>

typedef unsigned short u16;
typedef __attribute__((ext_vector_type(8))) short bf16x8;
typedef __attribute__((ext_vector_type(8))) unsigned short u16x8;
typedef __attribute__((ext_vector_type(4))) float f32x4;
typedef __attribute__((ext_vector_type(16))) float f32x16;
typedef __attribute__((ext_vector_type(4))) unsigned u32x4;
typedef __attribute__((ext_vector_type(2))) unsigned u32x2;

#define N_NODES 100000
#define IN_CH 128
#define HID 256
#define EMB 128
#define N_PAIRS 500000
#define BN_EPS 1e-5f

#define PBM 64  // pairs per block (kernel B); 64 nodes/block (kernel A)

// ---- bf16 helpers ----
__device__ __forceinline__ u16 f2bf(float f) {            // scalar RNE (prep kernel)
    unsigned u = __builtin_bit_cast(unsigned, f);
    unsigned r = u + 0x7FFFu + ((u >> 16) & 1u);
    return (u16)(r >> 16);
}
__device__ __forceinline__ float bf2f(u16 h) {
    unsigned u = ((unsigned)h) << 16;
    return __builtin_bit_cast(float, u);
}
// packed pair conversion -> v_cvt_pk_bf16_f32
__device__ __forceinline__ unsigned pk2(float a, float b) {
    __hip_bfloat162 h = __float22bfloat162_rn(make_float2(a, b));
    unsigned u;
    __builtin_memcpy(&u, &h, sizeof(u));
    return u;
}

// store 8 floats as bf16 at u16-index base
__device__ __forceinline__ void store8(u16* buf, int base, const float* v) {
    u32x4 hv;
    #pragma unroll
    for (int q = 0; q < 4; ++q) hv[q] = pk2(v[2 * q], v[2 * q + 1]);
    *reinterpret_cast<u32x4*>(&buf[base]) = hv;
}

// ---------------------------------------------------------------------------
// Weight prep.
// SW1 -> 32x32x16 A-operand frag layout: idx = ((mt32*32 + ks16)*64 + l)*8 + j
//   value = SW1[k][n], n = mt32*32 + (l&31), k = ks16*16 + (l>>5)*8 + j.
// SW2 -> 16x16x32 A layout (hi only). W1/W2 node weights keep hi+lo 16-shape.
// ---------------------------------------------------------------------------
__global__ __launch_bounds__(256) void prep_weights(
    const float* __restrict__ SW1, const float* __restrict__ SW2,
    const float* __restrict__ W1,  const float* __restrict__ W2,
    u16* __restrict__ w1h, u16* __restrict__ w2h,
    u16* __restrict__ w1nh, u16* __restrict__ w1nl,
    u16* __restrict__ w2nh, u16* __restrict__ w2nl)
{
    const int tid = blockIdx.x * 256 + threadIdx.x;
    if (tid < 131072) {                       // SW1 frags (32-shape): 8 mt32 x 32 ks16
        const int j = tid & 7, l = (tid >> 3) & 63, ks16 = (tid >> 9) & 31, mt32 = tid >> 14;
        const int n = mt32 * 32 + (l & 31);
        const int k = ks16 * 16 + ((l >> 5) << 3) + j;
        w1h[tid] = f2bf(SW1[(size_t)k * HID + n]);
    } else if (tid < 163840) {                // SW2 frags: 8 mt x 8 ks (16-shape)
        const int t2 = tid - 131072;
        const int j = t2 & 7, l = (t2 >> 3) & 63, ks = (t2 >> 9) & 7, mt = t2 >> 12;
        const int n = mt * 16 + (l & 15);
        const int k = ks * 32 + ((l >> 4) << 3) + j;
        w2h[t2] = f2bf(SW2[(size_t)k * (HID / 2) + n]);
    } else if (tid < 196608) {                // W1 node frags: 16 mt x 4 ks
        const int t3 = tid - 163840;
        const int j = t3 & 7, l = (t3 >> 3) & 63, ks = (t3 >> 9) & 3, mt = t3 >> 11;
        const int n = mt * 16 + (l & 15);
        const int k = ks * 32 + ((l >> 4) << 3) + j;
        const float v = W1[(size_t)k * HID + n];
        const u16 h = f2bf(v);
        w1nh[t3] = h;
        w1nl[t3] = f2bf(v - bf2f(h));
    } else if (tid < 229376) {                // W2 node frags: 8 mt x 8 ks
        const int t4 = tid - 196608;
        const int j = t4 & 7, l = (t4 >> 3) & 63, ks = (t4 >> 9) & 7, mt = t4 >> 12;
        const int n = mt * 16 + (l & 15);
        const int k = ks * 32 + ((l >> 4) << 3) + j;
        const float v = W2[(size_t)k * EMB + n];
        const u16 h = f2bf(v);
        w2nh[t4] = h;
        w2nl[t4] = f2bf(v - bf2f(h));
    }
}

// ---------------------------------------------------------------------------
// Kernel A (MFMA): node MLP. 64 nodes/block, 4 waves. Output z in BF16.
// 2-product split (exact weights) to keep z accurate. (unchanged from r15)
// ---------------------------------------------------------------------------
__global__ __launch_bounds__(256) void node_mfma_kernel(
    const float* __restrict__ x,
    const float* __restrict__ x_mean, const float* __restrict__ x_std,
    const float* __restrict__ b1,
    const float* __restrict__ bn_gamma, const float* __restrict__ bn_beta,
    const float* __restrict__ bn_mean,  const float* __restrict__ bn_var,
    const float* __restrict__ b2,
    const u16* __restrict__ w1nh, const u16* __restrict__ w1nl,
    const u16* __restrict__ w2nh, const u16* __restrict__ w2nl,
    u16* __restrict__ z)
{
    __shared__ __align__(16) u16 XF[8192];    // 16 KB: [slot 0..3][nt 0..3][512]
    __shared__ __align__(16) u16 HF[16384];   // 32 KB: [ks2 0..7][nt 0..3][512]

    const int t   = threadIdx.x;
    const int w   = t >> 6;
    const int l   = t & 63;
    const int l15 = l & 15;
    const int l4  = l >> 4;
    const int n0  = blockIdx.x * 64;
    const int nd  = (n0 + l < N_NODES) ? (n0 + l) : (N_NODES - 1);

    // ---- stage xf: thread (w,l) = node l, channels [w*32, w*32+32) ----
    {
        const float* xp = x + (size_t)nd * IN_CH + w * 32;
        float v[32];
        #pragma unroll
        for (int q = 0; q < 8; ++q)
            *reinterpret_cast<float4*>(&v[q * 4]) = *reinterpret_cast<const float4*>(xp + q * 4);
        #pragma unroll
        for (int q = 0; q < 8; ++q) {
            float4 m4 = *reinterpret_cast<const float4*>(x_mean + w * 32 + q * 4);
            float4 s4 = *reinterpret_cast<const float4*>(x_std  + w * 32 + q * 4);
            float mm[4] = {m4.x, m4.y, m4.z, m4.w};
            float ss[4] = {s4.x, s4.y, s4.z, s4.w};
            #pragma unroll
            for (int e = 0; e < 4; ++e) {
                float val = v[q * 4 + e];
                if (!isfinite(val)) val = 0.0f;
                val = (val - mm[e]) / ss[e];
                v[q * 4 + e] = fminf(fmaxf(val, -10.0f), 10.0f);
            }
        }
        #pragma unroll
        for (int q = 0; q < 4; ++q) {
            const int base = (w * 4 + l4) * 512 + (l15 + 16 * q) * 8;
            store8(XF, base, &v[q * 8]);
        }
    }
    __syncthreads();

    // ---- L1: acc[m][nt], wave owns mt {4w..4w+3}, K=128 ----
    f32x4 acc[4][4];
    #pragma unroll
    for (int m = 0; m < 4; ++m)
        #pragma unroll
        for (int nt = 0; nt < 4; ++nt) acc[m][nt] = (f32x4){0.f, 0.f, 0.f, 0.f};

    #pragma unroll
    for (int sl = 0; sl < 4; ++sl) {
        bf16x8 wh[4], wl[4];
        #pragma unroll
        for (int m = 0; m < 4; ++m) {
            const size_t bo = ((size_t)((w * 4 + m) * 4 + sl) * 64 + l) * 8;
            wh[m] = *reinterpret_cast<const bf16x8*>(&w1nh[bo]);
            wl[m] = *reinterpret_cast<const bf16x8*>(&w1nl[bo]);
        }
        bf16x8 fh[4];
        #pragma unroll
        for (int nt = 0; nt < 4; ++nt)
            fh[nt] = *reinterpret_cast<const bf16x8*>(&XF[(sl * 4 + nt) * 512 + l * 8]);
        __builtin_amdgcn_s_setprio(1);
        #pragma unroll
        for (int m = 0; m < 4; ++m)
            #pragma unroll
            for (int nt = 0; nt < 4; ++nt)
                acc[m][nt] = __builtin_amdgcn_mfma_f32_16x16x32_bf16(wh[m], fh[nt], acc[m][nt], 0, 0, 0);
        #pragma unroll
        for (int m = 0; m < 4; ++m)
            #pragma unroll
            for (int nt = 0; nt < 4; ++nt)
                acc[m][nt] = __builtin_amdgcn_mfma_f32_16x16x32_bf16(wl[m], fh[nt], acc[m][nt], 0, 0, 0);
        __builtin_amdgcn_s_setprio(0);
    }

    // ---- epilogue 1: BN + relu -> HF (bf16) ----
    #pragma unroll
    for (int m = 0; m < 4; ++m) {
        const int mt = w * 4 + m;
        const int nb = mt * 16 + l4 * 4;
        float4 b1v = *reinterpret_cast<const float4*>(b1 + nb);
        float4 gv  = *reinterpret_cast<const float4*>(bn_gamma + nb);
        float4 bev = *reinterpret_cast<const float4*>(bn_beta + nb);
        float4 mev = *reinterpret_cast<const float4*>(bn_mean + nb);
        float4 vav = *reinterpret_cast<const float4*>(bn_var + nb);
        float scale[4], shift[4];
        float bb[4] = {b1v.x, b1v.y, b1v.z, b1v.w};
        float gg[4] = {gv.x, gv.y, gv.z, gv.w};
        float be[4] = {bev.x, bev.y, bev.z, bev.w};
        float me[4] = {mev.x, mev.y, mev.z, mev.w};
        float va[4] = {vav.x, vav.y, vav.z, vav.w};
        #pragma unroll
        for (int r = 0; r < 4; ++r) {
            scale[r] = gg[r] * rsqrtf(va[r] + BN_EPS);
            shift[r] = (bb[r] - me[r]) * scale[r] + be[r];
        }
        #pragma unroll
        for (int nt = 0; nt < 4; ++nt) {
            float v[4];
            #pragma unroll
            for (int r = 0; r < 4; ++r)
                v[r] = fmaxf(fmaf(acc[m][nt][r], scale[r], shift[r]), 0.0f);
            u32x2 hv;
            hv[0] = pk2(v[0], v[1]);
            hv[1] = pk2(v[2], v[3]);
            const int base = ((mt >> 1) * 4 + nt) * 512
                           + (l15 + 16 * ((mt & 1) * 2 + (l4 >> 1))) * 8
                           + (l4 & 1) * 4;
            *reinterpret_cast<u32x2*>(&HF[base]) = hv;
        }
    }
    __syncthreads();

    // ---- L2: acc2[m2][nt], wave owns mt2 {2w, 2w+1}, K=256 ----
    f32x4 acc2[2][4];
    #pragma unroll
    for (int m2 = 0; m2 < 2; ++m2)
        #pragma unroll
        for (int nt = 0; nt < 4; ++nt) acc2[m2][nt] = (f32x4){0.f, 0.f, 0.f, 0.f};

    #pragma unroll
    for (int ks2 = 0; ks2 < 8; ++ks2) {
        bf16x8 wh2[2], wl2[2];
        #pragma unroll
        for (int m2 = 0; m2 < 2; ++m2) {
            const size_t bo = ((size_t)((w * 2 + m2) * 8 + ks2) * 64 + l) * 8;
            wh2[m2] = *reinterpret_cast<const bf16x8*>(&w2nh[bo]);
            wl2[m2] = *reinterpret_cast<const bf16x8*>(&w2nl[bo]);
        }
        bf16x8 fh[4];
        #pragma unroll
        for (int nt = 0; nt < 4; ++nt)
            fh[nt] = *reinterpret_cast<const bf16x8*>(&HF[(ks2 * 4 + nt) * 512 + l * 8]);
        __builtin_amdgcn_s_setprio(1);
        #pragma unroll
        for (int m2 = 0; m2 < 2; ++m2)
            #pragma unroll
            for (int nt = 0; nt < 4; ++nt)
                acc2[m2][nt] = __builtin_amdgcn_mfma_f32_16x16x32_bf16(wh2[m2], fh[nt], acc2[m2][nt], 0, 0, 0);
        #pragma unroll
        for (int m2 = 0; m2 < 2; ++m2)
            #pragma unroll
            for (int nt = 0; nt < 4; ++nt)
                acc2[m2][nt] = __builtin_amdgcn_mfma_f32_16x16x32_bf16(wl2[m2], fh[nt], acc2[m2][nt], 0, 0, 0);
        __builtin_amdgcn_s_setprio(0);
    }

    // ---- epilogue 2: z = bf16(relu(acc2 + b2)) -> global ----
    #pragma unroll
    for (int m2 = 0; m2 < 2; ++m2) {
        const int nb2 = (w * 2 + m2) * 16 + l4 * 4;
        float4 b2v = *reinterpret_cast<const float4*>(b2 + nb2);
        float bb[4] = {b2v.x, b2v.y, b2v.z, b2v.w};
        #pragma unroll
        for (int nt = 0; nt < 4; ++nt) {
            const int node = n0 + nt * 16 + l15;
            if (node < N_NODES) {
                float v0 = fmaxf(acc2[m2][nt][0] + bb[0], 0.0f);
                float v1 = fmaxf(acc2[m2][nt][1] + bb[1], 0.0f);
                float v2 = fmaxf(acc2[m2][nt][2] + bb[2], 0.0f);
                float v3 = fmaxf(acc2[m2][nt][3] + bb[3], 0.0f);
                u32x2 hv;
                hv[0] = pk2(v0, v1);
                hv[1] = pk2(v2, v3);
                *reinterpret_cast<u32x2*>(z + (size_t)node * EMB + nb2) = hv;
            }
        }
    }
}

// ---------------------------------------------------------------------------
// Kernel B: layer 1 on mfma_f32_32x32x16_bf16 (half the instructions, ~17%
// less matrix-pipe time). Wave owns mt32 {2w,2w+1} x nt32 {0,1}; acc 2x2 x
// f32x16 (64 AGPR, same as r15). r15's up-front 4-segment staging + 5-barrier
// schedule; layer 2 unchanged (16x16x32, hi-only).
// Buffer slot layout (16 slots x 512 u16): slot = ksl*2 + nt32, ksl 0..7;
//   slot holds B-frag: lane l -> feat[pair = nt32*32 + (l&31)]
//                               [kseg = ksl*16 + (l>>5)*8 + j]
// Segment -> global ks16: slots ksl<4 start kA, ksl>=4 start kB:
//   F0: kA=0  kB=8   (s/d ch0:64)     F1: kA=4  kB=12  (s/d ch64:128)
//   F2: kA=16 kB=24  (p/ad ch0:64)    F3: kA=20 kB=28  (p/ad ch64:128)
// ---------------------------------------------------------------------------
__global__ __launch_bounds__(256) void pair_mfma_kernel(
    const u16* __restrict__ z,
    const int* __restrict__ pairs,
    const float* __restrict__ logdeg,
    const u16* __restrict__ w1h,
    const u16* __restrict__ w2h,
    const float* __restrict__ SW1, const float* __restrict__ Sb1,
    const float* __restrict__ Sb2,
    const float* __restrict__ SW3, const float* __restrict__ Sb3,
    float* __restrict__ out)
{
    __shared__ __align__(16) u16 F0[8192];   // s/d  ch0:64
    __shared__ __align__(16) u16 F1[8192];   // s/d  ch64:128
    __shared__ __align__(16) u16 F2[8192];   // p/ad ch0:64
    __shared__ __align__(16) u16 F3[8192];   // p/ad ch64:128
    __shared__ float red[4][4][16];          // 1 KB

    const int t   = threadIdx.x;
    const int w   = t >> 6;        // wave 0..3
    const int l   = t & 63;
    const int l15 = l & 15;
    const int l4  = l >> 4;
    const int hi5 = l >> 5;        // lane half (32-shape)
    const int l31 = l & 31;
    const int p0  = blockIdx.x * PBM;

    // thread (w,l) stages pair l, channels [w*16, w*16+16) of a 64-ch half.
    // 32-shape frag bases (nw = pair>>5 of OWN pair l):
    const int nw  = l >> 5;
    const int sB0 = ((w * 2 + nw) * 64 + l31) * 8;             // s, half0 (j 0..7)
    const int sB1 = sB0 + 32 * 8;                              // s, half1
    const int dB0 = (((4 + w) * 2 + nw) * 64 + l31) * 8;       // d, half0
    const int dB1 = dB0 + 32 * 8;                              // d, half1

    const int gp  = (p0 + l < N_PAIRS) ? (p0 + l) : (N_PAIRS - 1);
    const int gsi = pairs[(size_t)gp * 2 + 0];
    const int gdi = pairs[(size_t)gp * 2 + 1];

    // ---- gather both halves (bf16, raw u16x8) ----
    const u16* zs0 = z + (size_t)gsi * EMB + w * 16;
    const u16* zd0 = z + (size_t)gdi * EMB + w * 16;
    u16x8 s00 = *reinterpret_cast<const u16x8*>(zs0);
    u16x8 s01 = *reinterpret_cast<const u16x8*>(zs0 + 8);
    u16x8 d00 = *reinterpret_cast<const u16x8*>(zd0);
    u16x8 d01 = *reinterpret_cast<const u16x8*>(zd0 + 8);
    u16x8 s10 = *reinterpret_cast<const u16x8*>(zs0 + 64);
    u16x8 s11 = *reinterpret_cast<const u16x8*>(zs0 + 72);
    u16x8 d10 = *reinterpret_cast<const u16x8*>(zd0 + 64);
    u16x8 d11 = *reinterpret_cast<const u16x8*>(zd0 + 72);

    // rebuild p = s~*d~, ad = |s~-d~| from held registers
    auto rebuildR = [&](u16x8 sa, u16x8 sb, u16x8 da, u16x8 db, float* pv, float* av) {
        #pragma unroll
        for (int qq = 0; qq < 8; ++qq) {
            const float s = bf2f(sa[qq]);
            const float d = bf2f(da[qq]);
            pv[qq] = s * d;
            av[qq] = fabsf(s - d);
        }
        #pragma unroll
        for (int qq = 0; qq < 8; ++qq) {
            const float s = bf2f(sb[qq]);
            const float d = bf2f(db[qq]);
            pv[8 + qq] = s * d;
            av[8 + qq] = fabsf(s - d);
        }
    };

    // ---- stage ALL FOUR segments up-front ----
    *reinterpret_cast<u16x8*>(&F0[sB0]) = s00;
    *reinterpret_cast<u16x8*>(&F0[sB1]) = s01;
    *reinterpret_cast<u16x8*>(&F0[dB0]) = d00;
    *reinterpret_cast<u16x8*>(&F0[dB1]) = d01;
    *reinterpret_cast<u16x8*>(&F1[sB0]) = s10;
    *reinterpret_cast<u16x8*>(&F1[sB1]) = s11;
    *reinterpret_cast<u16x8*>(&F1[dB0]) = d10;
    *reinterpret_cast<u16x8*>(&F1[dB1]) = d11;
    {
        float pv[16], av[16];
        rebuildR(s00, s01, d00, d01, pv, av);
        store8(F2, sB0, pv + 0);
        store8(F2, sB1, pv + 8);
        store8(F2, dB0, av + 0);
        store8(F2, dB1, av + 8);
        rebuildR(s10, s11, d10, d11, pv, av);
        store8(F3, sB0, pv + 0);
        store8(F3, sB1, pv + 8);
        store8(F3, dB0, av + 0);
        store8(F3, dB1, av + 8);
    }

    // ---- prefetch epilogue-1 logdeg: pairs (l&31) and 32+(l&31) ----
    float ldS2[2], ldD2[2];
    #pragma unroll
    for (int g2 = 0; g2 < 2; ++g2) {
        const int pidx = (p0 + g2 * 32 + l31 < N_PAIRS) ? (p0 + g2 * 32 + l31) : (N_PAIRS - 1);
        ldS2[g2] = logdeg[pairs[(size_t)pidx * 2 + 0]];
        ldD2[g2] = logdeg[pairs[(size_t)pidx * 2 + 1]];
    }

    __syncthreads();   // bar1: all features staged

    // ---- layer 1 (32x32x16): acc32[mi][nt32], mt32 = 2w + mi ----
    f32x16 acc32[2][2];
    #pragma unroll
    for (int mi = 0; mi < 2; ++mi)
        #pragma unroll
        for (int nt = 0; nt < 2; ++nt)
            #pragma unroll
            for (int r = 0; r < 16; ++r) acc32[mi][nt][r] = 0.0f;

    // one 128-K segment (8 ks16 steps); weight register dbuf across steps
    auto run_pass32 = [&](const u16* buf, int kA, int kB) {
        bf16x8 wh[2][2];
        #pragma unroll
        for (int mi = 0; mi < 2; ++mi) {
            const size_t bo = ((size_t)((2 * w + mi) * 32 + kA) * 64 + l) * 8;
            wh[0][mi] = *reinterpret_cast<const bf16x8*>(&w1h[bo]);
        }
        #pragma unroll
        for (int ksl = 0; ksl < 8; ++ksl) {
            const int cur = ksl & 1;
            if (ksl < 7) {
                const int gks = (ksl + 1 < 4) ? (kA + ksl + 1) : (kB + ksl - 3);
                #pragma unroll
                for (int mi = 0; mi < 2; ++mi) {
                    const size_t bo = ((size_t)((2 * w + mi) * 32 + gks) * 64 + l) * 8;
                    wh[cur ^ 1][mi] = *reinterpret_cast<const bf16x8*>(&w1h[bo]);
                }
            }
            bf16x8 fh[2];
            #pragma unroll
            for (int nt = 0; nt < 2; ++nt)
                fh[nt] = *reinterpret_cast<const bf16x8*>(&buf[((ksl * 2 + nt) * 64 + l) * 8]);
            __builtin_amdgcn_s_setprio(1);
            #pragma unroll
            for (int mi = 0; mi < 2; ++mi)
                #pragma unroll
                for (int nt = 0; nt < 2; ++nt)
                    acc32[mi][nt] = __builtin_amdgcn_mfma_f32_32x32x16_bf16(wh[cur][mi], fh[nt], acc32[mi][nt], 0, 0, 0);
            __builtin_amdgcn_s_setprio(0);
        }
    };

    // ---- layer 1: four uninterrupted passes ----
    run_pass32(F0, 0, 8);
    run_pass32(F2, 16, 24);
    run_pass32(F1, 4, 12);
    run_pass32(F3, 20, 28);
    __syncthreads();   // bar2: L1 done; F0/F1 reusable

    // ---- layer 2 (unchanged 16x16x32) ----
    f32x4 acc2[2][4];
    #pragma unroll
    for (int m2 = 0; m2 < 2; ++m2)
        #pragma unroll
        for (int nt = 0; nt < 4; ++nt) acc2[m2][nt] = (f32x4){0.f, 0.f, 0.f, 0.f};

    // epilogue-1 (32-shape C/D map): row n = mt32*32 + (r&3) + 8*(r>>2) + 4*hi5,
    // col pair = nt32*32 + l31. Writes layer-2 frag: ks2 = mt32 (g = mi),
    // slot = w*4 + nt2 (nt2 = nt32*2 + ((l>>4)&1)), lane = (l&15) + 16*q, j = 4*hi5 + rr.
    auto epi1_32 = [&](u16* buf, int mi) {
        const int mt32 = 2 * w + mi;
        #pragma unroll
        for (int nt = 0; nt < 2; ++nt) {
            const float lS = ldS2[nt];
            const float lD = ldD2[nt];
            const int nt2 = nt * 2 + ((l >> 4) & 1);
            #pragma unroll
            for (int q = 0; q < 4; ++q) {
                const int nb = mt32 * 32 + 8 * q + 4 * hi5;   // 4 consecutive n
                float sb[4], wa[4], wb[4];
                *reinterpret_cast<float4*>(sb) = *reinterpret_cast<const float4*>(&Sb1[nb]);
                *reinterpret_cast<float4*>(wa) = *reinterpret_cast<const float4*>(&SW1[(size_t)512 * HID + nb]);
                *reinterpret_cast<float4*>(wb) = *reinterpret_cast<const float4*>(&SW1[(size_t)513 * HID + nb]);
                float v[4];
                #pragma unroll
                for (int rr = 0; rr < 4; ++rr) {
                    float x0 = acc32[mi][nt][q * 4 + rr] + sb[rr];
                    x0 = fmaf(lS, wa[rr], x0);
                    x0 = fmaf(lD, wb[rr], x0);
                    v[rr] = fmaxf(x0, 0.0f);
                }
                u32x2 hv;
                hv[0] = pk2(v[0], v[1]);
                hv[1] = pk2(v[2], v[3]);
                const int base = (w * 4 + nt2) * 512 + (l15 + 16 * q) * 8 + 4 * hi5;
                *reinterpret_cast<u32x2*>(&buf[base]) = hv;
            }
        }
    };

    auto mfma2 = [&](const u16* buf, int g) {
        #pragma unroll
        for (int cs = 0; cs < 4; ++cs) {
            const int ks2 = cs * 2 + g;
            bf16x8 wh2[2];
            #pragma unroll
            for (int m2 = 0; m2 < 2; ++m2) {
                const size_t bo = ((size_t)((w * 2 + m2) * 8 + ks2) * 64 + l) * 8;
                wh2[m2] = *reinterpret_cast<const bf16x8*>(&w2h[bo]);
            }
            #pragma unroll
            for (int nh = 0; nh < 2; ++nh) {
                bf16x8 fh[2];
                #pragma unroll
                for (int e = 0; e < 2; ++e)
                    fh[e] = *reinterpret_cast<const bf16x8*>(&buf[(cs * 4 + nh * 2 + e) * 512 + l * 8]);
                __builtin_amdgcn_s_setprio(1);
                #pragma unroll
                for (int m2 = 0; m2 < 2; ++m2)
                    #pragma unroll
                    for (int e = 0; e < 2; ++e)
                        acc2[m2][nh * 2 + e] = __builtin_amdgcn_mfma_f32_16x16x32_bf16(wh2[m2], fh[e], acc2[m2][nh * 2 + e], 0, 0, 0);
                __builtin_amdgcn_s_setprio(0);
            }
        }
    };

    epi1_32(F0, 0);          // ks2 = 2w   (g = 0)
    __syncthreads();         // bar3: F0 s1-frags visible
    epi1_32(F1, 1);          // ks2 = 2w+1 (g = 1); overlaps mfma2(F0)
    mfma2(F0, 0);
    __syncthreads();         // bar4: F1 s1-frags visible
    mfma2(F1, 1);

    // ---- epilogue 2 + layer 3 ----
    {
        float part[4] = {0.f, 0.f, 0.f, 0.f};
        #pragma unroll
        for (int m2 = 0; m2 < 2; ++m2) {
            const int nb2 = (w * 2 + m2) * 16 + l4 * 4;
            float sb[4], w3[4];
            *reinterpret_cast<float4*>(sb) = *reinterpret_cast<const float4*>(&Sb2[nb2]);
            *reinterpret_cast<float4*>(w3) = *reinterpret_cast<const float4*>(&SW3[nb2]);
            #pragma unroll
            for (int nt = 0; nt < 4; ++nt)
                #pragma unroll
                for (int r = 0; r < 4; ++r)
                    part[nt] = fmaf(fmaxf(acc2[m2][nt][r] + sb[r], 0.0f), w3[r], part[nt]);
        }
        #pragma unroll
        for (int nt = 0; nt < 4; ++nt) {
            part[nt] += __shfl_xor(part[nt], 16);
            part[nt] += __shfl_xor(part[nt], 32);
        }
        if (l < 16) {
            #pragma unroll
            for (int nt = 0; nt < 4; ++nt) red[w][nt][l15] = part[nt];
        }
    }
    __syncthreads();   // bar5

    if (t < 64) {
        const int nt = t >> 4, pp = t & 15;
        float v = red[0][nt][pp] + red[1][nt][pp] + red[2][nt][pp] + red[3][nt][pp] + Sb3[0];
        if (isnan(v)) v = 0.0f;
        else if (isinf(v)) v = (v > 0.0f) ? 20.0f : -20.0f;
        const int pidx = p0 + nt * 16 + pp;
        if (pidx < N_PAIRS) out[pidx] = v;
    }
}

// ---------------------------------------------------------------------------
extern "C" void kernel_launch(void* const* d_in, const int* in_sizes, int n_in,
                              void* d_out, int out_size, void* d_ws, size_t ws_size,
                              hipStream_t stream)
{
    const float* x        = (const float*)d_in[0];
    // d_in[1] = edge_index : unused by the reference
    const int*   pairs    = (const int*)d_in[2];
    const float* x_mean   = (const float*)d_in[3];
    const float* x_std    = (const float*)d_in[4];
    const float* logdeg   = (const float*)d_in[5];
    const float* W1       = (const float*)d_in[6];
    const float* b1       = (const float*)d_in[7];
    const float* bn_gamma = (const float*)d_in[8];
    const float* bn_beta  = (const float*)d_in[9];
    const float* bn_mean  = (const float*)d_in[10];
    const float* bn_var   = (const float*)d_in[11];
    const float* W2       = (const float*)d_in[12];
    const float* b2       = (const float*)d_in[13];
    const float* SW1      = (const float*)d_in[14];
    const float* Sb1      = (const float*)d_in[15];
    const float* SW2      = (const float*)d_in[16];
    const float* Sb2      = (const float*)d_in[17];
    const float* SW3      = (const float*)d_in[18];
    const float* Sb3      = (const float*)d_in[19];

    float* outp = (float*)d_out;

    // ws layout (z bf16: 25,600,000 B)
    char* wsb = (char*)d_ws;
    u16* zbuf = (u16*)wsb;
    u16* w1h  = (u16*)(wsb + 25600000);                 // 262144 B
    u16* w2h  = (u16*)(wsb + 25862144);                 // 65536 B
    u16* w1nh = (u16*)(wsb + 25927680);                 // 65536 B
    u16* w1nl = (u16*)(wsb + 25993216);                 // 65536 B
    u16* w2nh = (u16*)(wsb + 26058752);                 // 65536 B
    u16* w2nl = (u16*)(wsb + 26124288);                 // 65536 B (end 26,189,824)

    prep_weights<<<896, 256, 0, stream>>>(SW1, SW2, W1, W2,
                                          w1h, w2h,
                                          w1nh, w1nl, w2nh, w2nl);

    node_mfma_kernel<<<(N_NODES + 63) / 64, 256, 0, stream>>>(
        x, x_mean, x_std, b1, bn_gamma, bn_beta, bn_mean, bn_var, b2,
        w1nh, w1nl, w2nh, w2nl, zbuf);

    pair_mfma_kernel<<<(N_PAIRS + PBM - 1) / PBM, 256, 0, stream>>>(
        zbuf, pairs, logdeg, w1h, w2h, SW1, Sb1, Sb2, SW3, Sb3, outp);
}

// Round 17
// 245.245 us; speedup vs baseline: 1.2138x; 1.2138x over previous
//
#include <hip/hip_runtime.h>
#include <hip/hip_bf16.h>
#include <math.h>

typedef unsigned short u16;
typedef __attribute__((ext_vector_type(8))) short bf16x8;
typedef __attribute__((ext_vector_type(8))) unsigned short u16x8;
typedef __attribute__((ext_vector_type(4))) float f32x4;
typedef __attribute__((ext_vector_type(4))) unsigned u32x4;
typedef __attribute__((ext_vector_type(2))) unsigned u32x2;

#define N_NODES 100000
#define IN_CH 128
#define HID 256
#define EMB 128
#define N_PAIRS 500000
#define BN_EPS 1e-5f

#define PBM 64  // pairs per block (kernel B); 64 nodes/block (kernel A)

// ---- bf16 helpers ----
__device__ __forceinline__ u16 f2bf(float f) {            // scalar RNE (prep kernel)
    unsigned u = __builtin_bit_cast(unsigned, f);
    unsigned r = u + 0x7FFFu + ((u >> 16) & 1u);
    return (u16)(r >> 16);
}
__device__ __forceinline__ float bf2f(u16 h) {
    unsigned u = ((unsigned)h) << 16;
    return __builtin_bit_cast(float, u);
}
// packed pair conversion -> v_cvt_pk_bf16_f32
__device__ __forceinline__ unsigned pk2(float a, float b) {
    __hip_bfloat162 h = __float22bfloat162_rn(make_float2(a, b));
    unsigned u;
    __builtin_memcpy(&u, &h, sizeof(u));
    return u;
}

// store 8 floats as bf16 at u16-index base
__device__ __forceinline__ void store8(u16* buf, int base, const float* v) {
    u32x4 hv;
    #pragma unroll
    for (int q = 0; q < 4; ++q) hv[q] = pk2(v[2 * q], v[2 * q + 1]);
    *reinterpret_cast<u32x4*>(&buf[base]) = hv;
}

// ---------------------------------------------------------------------------
// Weight prep into MFMA A-operand fragment-linear layout (weights on M-side):
// idx = ((mt*KS + ks)*64 + l)*8 + j ; value = W[k][n], n = mt*16 + (l&15),
// k = ks*32 + (l>>4)*8 + j. SW1/SW2 hi-only (1-product pair kernel);
// W1/W2 node weights keep hi+lo (2-product, z kept accurate).
// ---------------------------------------------------------------------------
__global__ __launch_bounds__(256) void prep_weights(
    const float* __restrict__ SW1, const float* __restrict__ SW2,
    const float* __restrict__ W1,  const float* __restrict__ W2,
    u16* __restrict__ w1h, u16* __restrict__ w2h,
    u16* __restrict__ w1nh, u16* __restrict__ w1nl,
    u16* __restrict__ w2nh, u16* __restrict__ w2nl)
{
    const int tid = blockIdx.x * 256 + threadIdx.x;
    if (tid < 131072) {                       // SW1 frags: 16 mt x 16 ks
        const int j = tid & 7, l = (tid >> 3) & 63, ks = (tid >> 9) & 15, mt = tid >> 13;
        const int n = mt * 16 + (l & 15);
        const int k = ks * 32 + ((l >> 4) << 3) + j;
        w1h[tid] = f2bf(SW1[(size_t)k * HID + n]);
    } else if (tid < 163840) {                // SW2 frags: 8 mt x 8 ks
        const int t2 = tid - 131072;
        const int j = t2 & 7, l = (t2 >> 3) & 63, ks = (t2 >> 9) & 7, mt = t2 >> 12;
        const int n = mt * 16 + (l & 15);
        const int k = ks * 32 + ((l >> 4) << 3) + j;
        w2h[t2] = f2bf(SW2[(size_t)k * (HID / 2) + n]);
    } else if (tid < 196608) {                // W1 node frags: 16 mt x 4 ks
        const int t3 = tid - 163840;
        const int j = t3 & 7, l = (t3 >> 3) & 63, ks = (t3 >> 9) & 3, mt = t3 >> 11;
        const int n = mt * 16 + (l & 15);
        const int k = ks * 32 + ((l >> 4) << 3) + j;
        const float v = W1[(size_t)k * HID + n];
        const u16 h = f2bf(v);
        w1nh[t3] = h;
        w1nl[t3] = f2bf(v - bf2f(h));
    } else if (tid < 229376) {                // W2 node frags: 8 mt x 8 ks
        const int t4 = tid - 196608;
        const int j = t4 & 7, l = (t4 >> 3) & 63, ks = (t4 >> 9) & 7, mt = t4 >> 12;
        const int n = mt * 16 + (l & 15);
        const int k = ks * 32 + ((l >> 4) << 3) + j;
        const float v = W2[(size_t)k * EMB + n];
        const u16 h = f2bf(v);
        w2nh[t4] = h;
        w2nl[t4] = f2bf(v - bf2f(h));
    }
}

// ---------------------------------------------------------------------------
// Kernel A (MFMA): node MLP. 64 nodes/block, 4 waves. Output z in BF16.
// 2-product split (exact weights) to keep z accurate. (unchanged from r15)
// ---------------------------------------------------------------------------
__global__ __launch_bounds__(256) void node_mfma_kernel(
    const float* __restrict__ x,
    const float* __restrict__ x_mean, const float* __restrict__ x_std,
    const float* __restrict__ b1,
    const float* __restrict__ bn_gamma, const float* __restrict__ bn_beta,
    const float* __restrict__ bn_mean,  const float* __restrict__ bn_var,
    const float* __restrict__ b2,
    const u16* __restrict__ w1nh, const u16* __restrict__ w1nl,
    const u16* __restrict__ w2nh, const u16* __restrict__ w2nl,
    u16* __restrict__ z)
{
    __shared__ __align__(16) u16 XF[8192];    // 16 KB: [slot 0..3][nt 0..3][512]
    __shared__ __align__(16) u16 HF[16384];   // 32 KB: [ks2 0..7][nt 0..3][512]

    const int t   = threadIdx.x;
    const int w   = t >> 6;
    const int l   = t & 63;
    const int l15 = l & 15;
    const int l4  = l >> 4;
    const int n0  = blockIdx.x * 64;
    const int nd  = (n0 + l < N_NODES) ? (n0 + l) : (N_NODES - 1);

    // ---- stage xf: thread (w,l) = node l, channels [w*32, w*32+32) ----
    {
        const float* xp = x + (size_t)nd * IN_CH + w * 32;
        float v[32];
        #pragma unroll
        for (int q = 0; q < 8; ++q)
            *reinterpret_cast<float4*>(&v[q * 4]) = *reinterpret_cast<const float4*>(xp + q * 4);
        #pragma unroll
        for (int q = 0; q < 8; ++q) {
            float4 m4 = *reinterpret_cast<const float4*>(x_mean + w * 32 + q * 4);
            float4 s4 = *reinterpret_cast<const float4*>(x_std  + w * 32 + q * 4);
            float mm[4] = {m4.x, m4.y, m4.z, m4.w};
            float ss[4] = {s4.x, s4.y, s4.z, s4.w};
            #pragma unroll
            for (int e = 0; e < 4; ++e) {
                float val = v[q * 4 + e];
                if (!isfinite(val)) val = 0.0f;
                val = (val - mm[e]) / ss[e];
                v[q * 4 + e] = fminf(fmaxf(val, -10.0f), 10.0f);
            }
        }
        #pragma unroll
        for (int q = 0; q < 4; ++q) {
            const int base = (w * 4 + l4) * 512 + (l15 + 16 * q) * 8;
            store8(XF, base, &v[q * 8]);
        }
    }
    __syncthreads();

    // ---- L1: acc[m][nt], wave owns mt {4w..4w+3}, K=128 ----
    f32x4 acc[4][4];
    #pragma unroll
    for (int m = 0; m < 4; ++m)
        #pragma unroll
        for (int nt = 0; nt < 4; ++nt) acc[m][nt] = (f32x4){0.f, 0.f, 0.f, 0.f};

    #pragma unroll
    for (int sl = 0; sl < 4; ++sl) {
        bf16x8 wh[4], wl[4];
        #pragma unroll
        for (int m = 0; m < 4; ++m) {
            const size_t bo = ((size_t)((w * 4 + m) * 4 + sl) * 64 + l) * 8;
            wh[m] = *reinterpret_cast<const bf16x8*>(&w1nh[bo]);
            wl[m] = *reinterpret_cast<const bf16x8*>(&w1nl[bo]);
        }
        bf16x8 fh[4];
        #pragma unroll
        for (int nt = 0; nt < 4; ++nt)
            fh[nt] = *reinterpret_cast<const bf16x8*>(&XF[(sl * 4 + nt) * 512 + l * 8]);
        __builtin_amdgcn_s_setprio(1);
        #pragma unroll
        for (int m = 0; m < 4; ++m)
            #pragma unroll
            for (int nt = 0; nt < 4; ++nt)
                acc[m][nt] = __builtin_amdgcn_mfma_f32_16x16x32_bf16(wh[m], fh[nt], acc[m][nt], 0, 0, 0);
        #pragma unroll
        for (int m = 0; m < 4; ++m)
            #pragma unroll
            for (int nt = 0; nt < 4; ++nt)
                acc[m][nt] = __builtin_amdgcn_mfma_f32_16x16x32_bf16(wl[m], fh[nt], acc[m][nt], 0, 0, 0);
        __builtin_amdgcn_s_setprio(0);
    }

    // ---- epilogue 1: BN + relu -> HF (bf16) ----
    #pragma unroll
    for (int m = 0; m < 4; ++m) {
        const int mt = w * 4 + m;
        const int nb = mt * 16 + l4 * 4;
        float4 b1v = *reinterpret_cast<const float4*>(b1 + nb);
        float4 gv  = *reinterpret_cast<const float4*>(bn_gamma + nb);
        float4 bev = *reinterpret_cast<const float4*>(bn_beta + nb);
        float4 mev = *reinterpret_cast<const float4*>(bn_mean + nb);
        float4 vav = *reinterpret_cast<const float4*>(bn_var + nb);
        float scale[4], shift[4];
        float bb[4] = {b1v.x, b1v.y, b1v.z, b1v.w};
        float gg[4] = {gv.x, gv.y, gv.z, gv.w};
        float be[4] = {bev.x, bev.y, bev.z, bev.w};
        float me[4] = {mev.x, mev.y, mev.z, mev.w};
        float va[4] = {vav.x, vav.y, vav.z, vav.w};
        #pragma unroll
        for (int r = 0; r < 4; ++r) {
            scale[r] = gg[r] * rsqrtf(va[r] + BN_EPS);
            shift[r] = (bb[r] - me[r]) * scale[r] + be[r];
        }
        #pragma unroll
        for (int nt = 0; nt < 4; ++nt) {
            float v[4];
            #pragma unroll
            for (int r = 0; r < 4; ++r)
                v[r] = fmaxf(fmaf(acc[m][nt][r], scale[r], shift[r]), 0.0f);
            u32x2 hv;
            hv[0] = pk2(v[0], v[1]);
            hv[1] = pk2(v[2], v[3]);
            const int base = ((mt >> 1) * 4 + nt) * 512
                           + (l15 + 16 * ((mt & 1) * 2 + (l4 >> 1))) * 8
                           + (l4 & 1) * 4;
            *reinterpret_cast<u32x2*>(&HF[base]) = hv;
        }
    }
    __syncthreads();

    // ---- L2: acc2[m2][nt], wave owns mt2 {2w, 2w+1}, K=256 ----
    f32x4 acc2[2][4];
    #pragma unroll
    for (int m2 = 0; m2 < 2; ++m2)
        #pragma unroll
        for (int nt = 0; nt < 4; ++nt) acc2[m2][nt] = (f32x4){0.f, 0.f, 0.f, 0.f};

    #pragma unroll
    for (int ks2 = 0; ks2 < 8; ++ks2) {
        bf16x8 wh2[2], wl2[2];
        #pragma unroll
        for (int m2 = 0; m2 < 2; ++m2) {
            const size_t bo = ((size_t)((w * 2 + m2) * 8 + ks2) * 64 + l) * 8;
            wh2[m2] = *reinterpret_cast<const bf16x8*>(&w2nh[bo]);
            wl2[m2] = *reinterpret_cast<const bf16x8*>(&w2nl[bo]);
        }
        bf16x8 fh[4];
        #pragma unroll
        for (int nt = 0; nt < 4; ++nt)
            fh[nt] = *reinterpret_cast<const bf16x8*>(&HF[(ks2 * 4 + nt) * 512 + l * 8]);
        __builtin_amdgcn_s_setprio(1);
        #pragma unroll
        for (int m2 = 0; m2 < 2; ++m2)
            #pragma unroll
            for (int nt = 0; nt < 4; ++nt)
                acc2[m2][nt] = __builtin_amdgcn_mfma_f32_16x16x32_bf16(wh2[m2], fh[nt], acc2[m2][nt], 0, 0, 0);
        #pragma unroll
        for (int m2 = 0; m2 < 2; ++m2)
            #pragma unroll
            for (int nt = 0; nt < 4; ++nt)
                acc2[m2][nt] = __builtin_amdgcn_mfma_f32_16x16x32_bf16(wl2[m2], fh[nt], acc2[m2][nt], 0, 0, 0);
        __builtin_amdgcn_s_setprio(0);
    }

    // ---- epilogue 2: z = bf16(relu(acc2 + b2)) -> global ----
    #pragma unroll
    for (int m2 = 0; m2 < 2; ++m2) {
        const int nb2 = (w * 2 + m2) * 16 + l4 * 4;
        float4 b2v = *reinterpret_cast<const float4*>(b2 + nb2);
        float bb[4] = {b2v.x, b2v.y, b2v.z, b2v.w};
        #pragma unroll
        for (int nt = 0; nt < 4; ++nt) {
            const int node = n0 + nt * 16 + l15;
            if (node < N_NODES) {
                float v0 = fmaxf(acc2[m2][nt][0] + bb[0], 0.0f);
                float v1 = fmaxf(acc2[m2][nt][1] + bb[1], 0.0f);
                float v2 = fmaxf(acc2[m2][nt][2] + bb[2], 0.0f);
                float v3 = fmaxf(acc2[m2][nt][3] + bb[3], 0.0f);
                u32x2 hv;
                hv[0] = pk2(v0, v1);
                hv[1] = pk2(v2, v3);
                *reinterpret_cast<u32x2*>(z + (size_t)node * EMB + nb2) = hv;
            }
        }
    }
}

// ---------------------------------------------------------------------------
// Kernel B (MFMA): r15 structure (64 pairs/block, 4 waves, 4 segments staged
// up-front, 5 barriers, 1-product 16x16x32) + 1-step FEATURE register
// double-buffer in run_pass (prefetch step st+1's frags before step st's
// MFMA burst) to hide ds_read latency at 2 waves/SIMD.
// ---------------------------------------------------------------------------
__global__ __launch_bounds__(256) void pair_mfma_kernel(
    const u16* __restrict__ z,
    const int* __restrict__ pairs,
    const float* __restrict__ logdeg,
    const u16* __restrict__ w1h,
    const u16* __restrict__ w2h,
    const float* __restrict__ SW1, const float* __restrict__ Sb1,
    const float* __restrict__ Sb2,
    const float* __restrict__ SW3, const float* __restrict__ Sb3,
    float* __restrict__ out)
{
    __shared__ __align__(16) u16 F0[8192];   // sd  ch0:64   (ks 0,1,4,5)
    __shared__ __align__(16) u16 F1[8192];   // sd  ch64:128 (ks 2,3,6,7)
    __shared__ __align__(16) u16 F2[8192];   // p|ad ch0:64  (ks 8,9,12,13)
    __shared__ __align__(16) u16 F3[8192];   // p|ad ch64:128(ks 10,11,14,15)
    __shared__ float red[4][4][16];          // 1 KB

    const int t   = threadIdx.x;
    const int w   = t >> 6;        // wave 0..3
    const int l   = t & 63;
    const int l15 = l & 15;
    const int l4  = l >> 4;
    const int p0  = blockIdx.x * PBM;

    // thread (w,l): pair l, channels [w*16, w*16+16) of a 64-ch half.
    const int qb  = (w & 1) * 2;
    const int bS0 = (((w >> 1)) * 4 + l4) * 512 + (l15 + 16 * (qb + 0)) * 8;
    const int bS1 = (((w >> 1)) * 4 + l4) * 512 + (l15 + 16 * (qb + 1)) * 8;
    const int bD0 = ((2 + (w >> 1)) * 4 + l4) * 512 + (l15 + 16 * (qb + 0)) * 8;
    const int bD1 = ((2 + (w >> 1)) * 4 + l4) * 512 + (l15 + 16 * (qb + 1)) * 8;

    const int gp  = (p0 + l < N_PAIRS) ? (p0 + l) : (N_PAIRS - 1);
    const int gsi = pairs[(size_t)gp * 2 + 0];
    const int gdi = pairs[(size_t)gp * 2 + 1];

    // ---- gather both halves (bf16, raw u16x8) ----
    const u16* zs0 = z + (size_t)gsi * EMB + w * 16;
    const u16* zd0 = z + (size_t)gdi * EMB + w * 16;
    u16x8 s00 = *reinterpret_cast<const u16x8*>(zs0);
    u16x8 s01 = *reinterpret_cast<const u16x8*>(zs0 + 8);
    u16x8 d00 = *reinterpret_cast<const u16x8*>(zd0);
    u16x8 d01 = *reinterpret_cast<const u16x8*>(zd0 + 8);
    u16x8 s10 = *reinterpret_cast<const u16x8*>(zs0 + 64);
    u16x8 s11 = *reinterpret_cast<const u16x8*>(zs0 + 72);
    u16x8 d10 = *reinterpret_cast<const u16x8*>(zd0 + 64);
    u16x8 d11 = *reinterpret_cast<const u16x8*>(zd0 + 72);

    // rebuild p = s~*d~, ad = |s~-d~| from held registers
    auto rebuildR = [&](u16x8 sa, u16x8 sb, u16x8 da, u16x8 db, float* pv, float* av) {
        #pragma unroll
        for (int qq = 0; qq < 8; ++qq) {
            const float s = bf2f(sa[qq]);
            const float d = bf2f(da[qq]);
            pv[qq] = s * d;
            av[qq] = fabsf(s - d);
        }
        #pragma unroll
        for (int qq = 0; qq < 8; ++qq) {
            const float s = bf2f(sb[qq]);
            const float d = bf2f(db[qq]);
            pv[8 + qq] = s * d;
            av[8 + qq] = fabsf(s - d);
        }
    };

    // ---- stage ALL FOUR segments up-front ----
    *reinterpret_cast<u16x8*>(&F0[bS0]) = s00;
    *reinterpret_cast<u16x8*>(&F0[bS1]) = s01;
    *reinterpret_cast<u16x8*>(&F0[bD0]) = d00;
    *reinterpret_cast<u16x8*>(&F0[bD1]) = d01;
    *reinterpret_cast<u16x8*>(&F1[bS0]) = s10;
    *reinterpret_cast<u16x8*>(&F1[bS1]) = s11;
    *reinterpret_cast<u16x8*>(&F1[bD0]) = d10;
    *reinterpret_cast<u16x8*>(&F1[bD1]) = d11;
    {
        float pv[16], av[16];
        rebuildR(s00, s01, d00, d01, pv, av);
        store8(F2, bS0, pv + 0);
        store8(F2, bS1, pv + 8);
        store8(F2, bD0, av + 0);
        store8(F2, bD1, av + 8);
        rebuildR(s10, s11, d10, d11, pv, av);
        store8(F3, bS0, pv + 0);
        store8(F3, bS1, pv + 8);
        store8(F3, bD0, av + 0);
        store8(F3, bD1, av + 8);
    }

    // ---- prefetch epilogue-1 gather data ----
    float ldS[4], ldD[4];
    #pragma unroll
    for (int nt = 0; nt < 4; ++nt) {
        const int pidx = (p0 + nt * 16 + l15 < N_PAIRS) ? (p0 + nt * 16 + l15) : (N_PAIRS - 1);
        ldS[nt] = logdeg[pairs[(size_t)pidx * 2 + 0]];
        ldD[nt] = logdeg[pairs[(size_t)pidx * 2 + 1]];
    }

    __syncthreads();   // bar1: all features staged

    f32x4 acc[4][4];
    #pragma unroll
    for (int m = 0; m < 4; ++m)
        #pragma unroll
        for (int nt = 0; nt < 4; ++nt) acc[m][nt] = (f32x4){0.f, 0.f, 0.f, 0.f};

    // one 128-K segment; weight dbuf across sl AND feature dbuf across steps
    auto run_pass = [&](const u16* buf, int k0, int k1, int k2, int k3) {
        const int ksg[4] = {k0, k1, k2, k3};
        bf16x8 wh[2][4];
        #pragma unroll
        for (int m = 0; m < 4; ++m) {
            const size_t bo = ((size_t)((w * 4 + m) * 16 + ksg[0]) * 64 + l) * 8;
            wh[0][m] = *reinterpret_cast<const bf16x8*>(&w1h[bo]);
        }
        bf16x8 fh[2][2];
        #pragma unroll
        for (int e = 0; e < 2; ++e)
            fh[0][e] = *reinterpret_cast<const bf16x8*>(&buf[(e) * 512 + l * 8]);

        #pragma unroll
        for (int st = 0; st < 8; ++st) {
            const int sl   = st >> 1;
            const int nh   = st & 1;
            const int fcur = st & 1;
            const int wcur = sl & 1;
            if (nh == 0 && sl < 3) {
                #pragma unroll
                for (int m = 0; m < 4; ++m) {
                    const size_t bo = ((size_t)((w * 4 + m) * 16 + ksg[sl + 1]) * 64 + l) * 8;
                    wh[wcur ^ 1][m] = *reinterpret_cast<const bf16x8*>(&w1h[bo]);
                }
            }
            if (st < 7) {
                const int nsl = (st + 1) >> 1;
                const int nnh = (st + 1) & 1;
                #pragma unroll
                for (int e = 0; e < 2; ++e)
                    fh[fcur ^ 1][e] = *reinterpret_cast<const bf16x8*>(&buf[(nsl * 4 + nnh * 2 + e) * 512 + l * 8]);
            }
            __builtin_amdgcn_s_setprio(1);
            #pragma unroll
            for (int m = 0; m < 4; ++m)
                #pragma unroll
                for (int e = 0; e < 2; ++e)
                    acc[m][nh * 2 + e] = __builtin_amdgcn_mfma_f32_16x16x32_bf16(wh[wcur][m], fh[fcur][e], acc[m][nh * 2 + e], 0, 0, 0);
            __builtin_amdgcn_s_setprio(0);
        }
    };

    // ---- layer 1: four uninterrupted passes ----
    run_pass(F0, 0, 1, 4, 5);
    run_pass(F2, 8, 9, 12, 13);
    run_pass(F1, 2, 3, 6, 7);
    run_pass(F3, 10, 11, 14, 15);
    __syncthreads();   // bar2: L1 done; F0/F1 reusable

    // ---- layer 2 ----
    f32x4 acc2[2][4];
    #pragma unroll
    for (int m2 = 0; m2 < 2; ++m2)
        #pragma unroll
        for (int nt = 0; nt < 4; ++nt) acc2[m2][nt] = (f32x4){0.f, 0.f, 0.f, 0.f};

    auto epi1 = [&](u16* buf, int g) {
        #pragma unroll
        for (int mm = 0; mm < 2; ++mm) {
            const int m  = 2 * g + mm;
            const int mt = w * 4 + m;
            const int nb = mt * 16 + l4 * 4;
            float sb[4], wa[4], wb[4];
            *reinterpret_cast<float4*>(sb) = *reinterpret_cast<const float4*>(&Sb1[nb]);
            *reinterpret_cast<float4*>(wa) = *reinterpret_cast<const float4*>(&SW1[(size_t)512 * HID + nb]);
            *reinterpret_cast<float4*>(wb) = *reinterpret_cast<const float4*>(&SW1[(size_t)513 * HID + nb]);
            #pragma unroll
            for (int nt = 0; nt < 4; ++nt) {
                float v[4];
                #pragma unroll
                for (int r = 0; r < 4; ++r) {
                    float x0 = acc[m][nt][r] + sb[r];
                    x0 = fmaf(ldS[nt], wa[r], x0);
                    x0 = fmaf(ldD[nt], wb[r], x0);
                    v[r] = fmaxf(x0, 0.0f);
                }
                u32x2 hv;
                hv[0] = pk2(v[0], v[1]);
                hv[1] = pk2(v[2], v[3]);
                const int base = (w * 4 + nt) * 512
                               + (l15 + 16 * ((m & 1) * 2 + (l4 >> 1))) * 8
                               + (l4 & 1) * 4;
                *reinterpret_cast<u32x2*>(&buf[base]) = hv;
            }
        }
    };

    auto mfma2 = [&](const u16* buf, int g) {
        #pragma unroll
        for (int cs = 0; cs < 4; ++cs) {
            const int ks2 = cs * 2 + g;
            bf16x8 wh2[2];
            #pragma unroll
            for (int m2 = 0; m2 < 2; ++m2) {
                const size_t bo = ((size_t)((w * 2 + m2) * 8 + ks2) * 64 + l) * 8;
                wh2[m2] = *reinterpret_cast<const bf16x8*>(&w2h[bo]);
            }
            #pragma unroll
            for (int nh = 0; nh < 2; ++nh) {
                bf16x8 fh[2];
                #pragma unroll
                for (int e = 0; e < 2; ++e)
                    fh[e] = *reinterpret_cast<const bf16x8*>(&buf[(cs * 4 + nh * 2 + e) * 512 + l * 8]);
                __builtin_amdgcn_s_setprio(1);
                #pragma unroll
                for (int m2 = 0; m2 < 2; ++m2)
                    #pragma unroll
                    for (int e = 0; e < 2; ++e)
                        acc2[m2][nh * 2 + e] = __builtin_amdgcn_mfma_f32_16x16x32_bf16(wh2[m2], fh[e], acc2[m2][nh * 2 + e], 0, 0, 0);
                __builtin_amdgcn_s_setprio(0);
            }
        }
    };

    epi1(F0, 0);
    __syncthreads();         // bar3: F0 s1-frags visible
    epi1(F1, 1);             // overlaps mfma2(F0)
    mfma2(F0, 0);
    __syncthreads();         // bar4: F1 s1-frags visible
    mfma2(F1, 1);

    // ---- epilogue 2 + layer 3 ----
    {
        float part[4] = {0.f, 0.f, 0.f, 0.f};
        #pragma unroll
        for (int m2 = 0; m2 < 2; ++m2) {
            const int nb2 = (w * 2 + m2) * 16 + l4 * 4;
            float sb[4], w3[4];
            *reinterpret_cast<float4*>(sb) = *reinterpret_cast<const float4*>(&Sb2[nb2]);
            *reinterpret_cast<float4*>(w3) = *reinterpret_cast<const float4*>(&SW3[nb2]);
            #pragma unroll
            for (int nt = 0; nt < 4; ++nt)
                #pragma unroll
                for (int r = 0; r < 4; ++r)
                    part[nt] = fmaf(fmaxf(acc2[m2][nt][r] + sb[r], 0.0f), w3[r], part[nt]);
        }
        #pragma unroll
        for (int nt = 0; nt < 4; ++nt) {
            part[nt] += __shfl_xor(part[nt], 16);
            part[nt] += __shfl_xor(part[nt], 32);
        }
        if (l < 16) {
            #pragma unroll
            for (int nt = 0; nt < 4; ++nt) red[w][nt][l15] = part[nt];
        }
    }
    __syncthreads();   // bar5

    if (t < 64) {
        const int nt = t >> 4, pp = t & 15;
        float v = red[0][nt][pp] + red[1][nt][pp] + red[2][nt][pp] + red[3][nt][pp] + Sb3[0];
        if (isnan(v)) v = 0.0f;
        else if (isinf(v)) v = (v > 0.0f) ? 20.0f : -20.0f;
        const int pidx = p0 + nt * 16 + pp;
        if (pidx < N_PAIRS) out[pidx] = v;
    }
}

// ---------------------------------------------------------------------------
extern "C" void kernel_launch(void* const* d_in, const int* in_sizes, int n_in,
                              void* d_out, int out_size, void* d_ws, size_t ws_size,
                              hipStream_t stream)
{
    const float* x        = (const float*)d_in[0];
    // d_in[1] = edge_index : unused by the reference
    const int*   pairs    = (const int*)d_in[2];
    const float* x_mean   = (const float*)d_in[3];
    const float* x_std    = (const float*)d_in[4];
    const float* logdeg   = (const float*)d_in[5];
    const float* W1       = (const float*)d_in[6];
    const float* b1       = (const float*)d_in[7];
    const float* bn_gamma = (const float*)d_in[8];
    const float* bn_beta  = (const float*)d_in[9];
    const float* bn_mean  = (const float*)d_in[10];
    const float* bn_var   = (const float*)d_in[11];
    const float* W2       = (const float*)d_in[12];
    const float* b2       = (const float*)d_in[13];
    const float* SW1      = (const float*)d_in[14];
    const float* Sb1      = (const float*)d_in[15];
    const float* SW2      = (const float*)d_in[16];
    const float* Sb2      = (const float*)d_in[17];
    const float* SW3      = (const float*)d_in[18];
    const float* Sb3      = (const float*)d_in[19];

    float* outp = (float*)d_out;

    // ws layout (z bf16: 25,600,000 B)
    char* wsb = (char*)d_ws;
    u16* zbuf = (u16*)wsb;
    u16* w1h  = (u16*)(wsb + 25600000);                 // 262144 B
    u16* w2h  = (u16*)(wsb + 25862144);                 // 65536 B
    u16* w1nh = (u16*)(wsb + 25927680);                 // 65536 B
    u16* w1nl = (u16*)(wsb + 25993216);                 // 65536 B
    u16* w2nh = (u16*)(wsb + 26058752);                 // 65536 B
    u16* w2nl = (u16*)(wsb + 26124288);                 // 65536 B (end 26,189,824)

    prep_weights<<<896, 256, 0, stream>>>(SW1, SW2, W1, W2,
                                          w1h, w2h,
                                          w1nh, w1nl, w2nh, w2nl);

    node_mfma_kernel<<<(N_NODES + 63) / 64, 256, 0, stream>>>(
        x, x_mean, x_std, b1, bn_gamma, bn_beta, bn_mean, bn_var, b2,
        w1nh, w1nl, w2nh, w2nl, zbuf);

    pair_mfma_kernel<<<(N_PAIRS + PBM - 1) / PBM, 256, 0, stream>>>(
        zbuf, pairs, logdeg, w1h, w2h, SW1, Sb1, Sb2, SW3, Sb3, outp);
}

// Round 18
// 237.913 us; speedup vs baseline: 1.2512x; 1.0308x over previous
//
#include <hip/hip_runtime.h>
#include <hip/hip_bf16.h>
#include <math.h>

typedef unsigned short u16;
typedef __attribute__((ext_vector_type(8))) short bf16x8;
typedef __attribute__((ext_vector_type(8))) unsigned short u16x8;
typedef __attribute__((ext_vector_type(4))) float f32x4;
typedef __attribute__((ext_vector_type(4))) unsigned u32x4;
typedef __attribute__((ext_vector_type(2))) unsigned u32x2;

#define N_NODES 100000
#define IN_CH 128
#define HID 256
#define EMB 128
#define N_PAIRS 500000
#define BN_EPS 1e-5f

#define PBM 64  // pairs per block (kernel B); 64 nodes/block (kernel A)

// ---- bf16 helpers ----
__device__ __forceinline__ u16 f2bf(float f) {            // scalar RNE (prep kernel)
    unsigned u = __builtin_bit_cast(unsigned, f);
    unsigned r = u + 0x7FFFu + ((u >> 16) & 1u);
    return (u16)(r >> 16);
}
__device__ __forceinline__ float bf2f(u16 h) {
    unsigned u = ((unsigned)h) << 16;
    return __builtin_bit_cast(float, u);
}
// packed pair conversion -> v_cvt_pk_bf16_f32
__device__ __forceinline__ unsigned pk2(float a, float b) {
    __hip_bfloat162 h = __float22bfloat162_rn(make_float2(a, b));
    unsigned u;
    __builtin_memcpy(&u, &h, sizeof(u));
    return u;
}

// store 8 floats as bf16 at u16-index base
__device__ __forceinline__ void store8(u16* buf, int base, const float* v) {
    u32x4 hv;
    #pragma unroll
    for (int q = 0; q < 4; ++q) hv[q] = pk2(v[2 * q], v[2 * q + 1]);
    *reinterpret_cast<u32x4*>(&buf[base]) = hv;
}

// ---------------------------------------------------------------------------
// Weight prep into MFMA A-operand fragment-linear layout (weights on M-side):
// idx = ((mt*KS + ks)*64 + l)*8 + j ; value = W[k][n], n = mt*16 + (l&15),
// k = ks*32 + (l>>4)*8 + j. SW1/SW2 hi-only (1-product pair kernel);
// W1/W2 node weights keep hi+lo (2-product, z kept accurate).
// ---------------------------------------------------------------------------
__global__ __launch_bounds__(256) void prep_weights(
    const float* __restrict__ SW1, const float* __restrict__ SW2,
    const float* __restrict__ W1,  const float* __restrict__ W2,
    u16* __restrict__ w1h, u16* __restrict__ w2h,
    u16* __restrict__ w1nh, u16* __restrict__ w1nl,
    u16* __restrict__ w2nh, u16* __restrict__ w2nl)
{
    const int tid = blockIdx.x * 256 + threadIdx.x;
    if (tid < 131072) {                       // SW1 frags: 16 mt x 16 ks
        const int j = tid & 7, l = (tid >> 3) & 63, ks = (tid >> 9) & 15, mt = tid >> 13;
        const int n = mt * 16 + (l & 15);
        const int k = ks * 32 + ((l >> 4) << 3) + j;
        w1h[tid] = f2bf(SW1[(size_t)k * HID + n]);
    } else if (tid < 163840) {                // SW2 frags: 8 mt x 8 ks
        const int t2 = tid - 131072;
        const int j = t2 & 7, l = (t2 >> 3) & 63, ks = (t2 >> 9) & 7, mt = t2 >> 12;
        const int n = mt * 16 + (l & 15);
        const int k = ks * 32 + ((l >> 4) << 3) + j;
        w2h[t2] = f2bf(SW2[(size_t)k * (HID / 2) + n]);
    } else if (tid < 196608) {                // W1 node frags: 16 mt x 4 ks
        const int t3 = tid - 163840;
        const int j = t3 & 7, l = (t3 >> 3) & 63, ks = (t3 >> 9) & 3, mt = t3 >> 11;
        const int n = mt * 16 + (l & 15);
        const int k = ks * 32 + ((l >> 4) << 3) + j;
        const float v = W1[(size_t)k * HID + n];
        const u16 h = f2bf(v);
        w1nh[t3] = h;
        w1nl[t3] = f2bf(v - bf2f(h));
    } else if (tid < 229376) {                // W2 node frags: 8 mt x 8 ks
        const int t4 = tid - 196608;
        const int j = t4 & 7, l = (t4 >> 3) & 63, ks = (t4 >> 9) & 7, mt = t4 >> 12;
        const int n = mt * 16 + (l & 15);
        const int k = ks * 32 + ((l >> 4) << 3) + j;
        const float v = W2[(size_t)k * EMB + n];
        const u16 h = f2bf(v);
        w2nh[t4] = h;
        w2nl[t4] = f2bf(v - bf2f(h));
    }
}

// ---------------------------------------------------------------------------
// Kernel A (MFMA): node MLP. 64 nodes/block, 4 waves. Output z in BF16.
// 2-product split (exact weights) to keep z accurate. (unchanged)
// ---------------------------------------------------------------------------
__global__ __launch_bounds__(256) void node_mfma_kernel(
    const float* __restrict__ x,
    const float* __restrict__ x_mean, const float* __restrict__ x_std,
    const float* __restrict__ b1,
    const float* __restrict__ bn_gamma, const float* __restrict__ bn_beta,
    const float* __restrict__ bn_mean,  const float* __restrict__ bn_var,
    const float* __restrict__ b2,
    const u16* __restrict__ w1nh, const u16* __restrict__ w1nl,
    const u16* __restrict__ w2nh, const u16* __restrict__ w2nl,
    u16* __restrict__ z)
{
    __shared__ __align__(16) u16 XF[8192];    // 16 KB: [slot 0..3][nt 0..3][512]
    __shared__ __align__(16) u16 HF[16384];   // 32 KB: [ks2 0..7][nt 0..3][512]

    const int t   = threadIdx.x;
    const int w   = t >> 6;
    const int l   = t & 63;
    const int l15 = l & 15;
    const int l4  = l >> 4;
    const int n0  = blockIdx.x * 64;
    const int nd  = (n0 + l < N_NODES) ? (n0 + l) : (N_NODES - 1);

    // ---- stage xf: thread (w,l) = node l, channels [w*32, w*32+32) ----
    {
        const float* xp = x + (size_t)nd * IN_CH + w * 32;
        float v[32];
        #pragma unroll
        for (int q = 0; q < 8; ++q)
            *reinterpret_cast<float4*>(&v[q * 4]) = *reinterpret_cast<const float4*>(xp + q * 4);
        #pragma unroll
        for (int q = 0; q < 8; ++q) {
            float4 m4 = *reinterpret_cast<const float4*>(x_mean + w * 32 + q * 4);
            float4 s4 = *reinterpret_cast<const float4*>(x_std  + w * 32 + q * 4);
            float mm[4] = {m4.x, m4.y, m4.z, m4.w};
            float ss[4] = {s4.x, s4.y, s4.z, s4.w};
            #pragma unroll
            for (int e = 0; e < 4; ++e) {
                float val = v[q * 4 + e];
                if (!isfinite(val)) val = 0.0f;
                val = (val - mm[e]) / ss[e];
                v[q * 4 + e] = fminf(fmaxf(val, -10.0f), 10.0f);
            }
        }
        #pragma unroll
        for (int q = 0; q < 4; ++q) {
            const int base = (w * 4 + l4) * 512 + (l15 + 16 * q) * 8;
            store8(XF, base, &v[q * 8]);
        }
    }
    __syncthreads();

    // ---- L1: acc[m][nt], wave owns mt {4w..4w+3}, K=128 ----
    f32x4 acc[4][4];
    #pragma unroll
    for (int m = 0; m < 4; ++m)
        #pragma unroll
        for (int nt = 0; nt < 4; ++nt) acc[m][nt] = (f32x4){0.f, 0.f, 0.f, 0.f};

    #pragma unroll
    for (int sl = 0; sl < 4; ++sl) {
        bf16x8 wh[4], wl[4];
        #pragma unroll
        for (int m = 0; m < 4; ++m) {
            const size_t bo = ((size_t)((w * 4 + m) * 4 + sl) * 64 + l) * 8;
            wh[m] = *reinterpret_cast<const bf16x8*>(&w1nh[bo]);
            wl[m] = *reinterpret_cast<const bf16x8*>(&w1nl[bo]);
        }
        bf16x8 fh[4];
        #pragma unroll
        for (int nt = 0; nt < 4; ++nt)
            fh[nt] = *reinterpret_cast<const bf16x8*>(&XF[(sl * 4 + nt) * 512 + l * 8]);
        __builtin_amdgcn_s_setprio(1);
        #pragma unroll
        for (int m = 0; m < 4; ++m)
            #pragma unroll
            for (int nt = 0; nt < 4; ++nt)
                acc[m][nt] = __builtin_amdgcn_mfma_f32_16x16x32_bf16(wh[m], fh[nt], acc[m][nt], 0, 0, 0);
        #pragma unroll
        for (int m = 0; m < 4; ++m)
            #pragma unroll
            for (int nt = 0; nt < 4; ++nt)
                acc[m][nt] = __builtin_amdgcn_mfma_f32_16x16x32_bf16(wl[m], fh[nt], acc[m][nt], 0, 0, 0);
        __builtin_amdgcn_s_setprio(0);
    }

    // ---- epilogue 1: BN + relu -> HF (bf16) ----
    #pragma unroll
    for (int m = 0; m < 4; ++m) {
        const int mt = w * 4 + m;
        const int nb = mt * 16 + l4 * 4;
        float4 b1v = *reinterpret_cast<const float4*>(b1 + nb);
        float4 gv  = *reinterpret_cast<const float4*>(bn_gamma + nb);
        float4 bev = *reinterpret_cast<const float4*>(bn_beta + nb);
        float4 mev = *reinterpret_cast<const float4*>(bn_mean + nb);
        float4 vav = *reinterpret_cast<const float4*>(bn_var + nb);
        float scale[4], shift[4];
        float bb[4] = {b1v.x, b1v.y, b1v.z, b1v.w};
        float gg[4] = {gv.x, gv.y, gv.z, gv.w};
        float be[4] = {bev.x, bev.y, bev.z, bev.w};
        float me[4] = {mev.x, mev.y, mev.z, mev.w};
        float va[4] = {vav.x, vav.y, vav.z, vav.w};
        #pragma unroll
        for (int r = 0; r < 4; ++r) {
            scale[r] = gg[r] * rsqrtf(va[r] + BN_EPS);
            shift[r] = (bb[r] - me[r]) * scale[r] + be[r];
        }
        #pragma unroll
        for (int nt = 0; nt < 4; ++nt) {
            float v[4];
            #pragma unroll
            for (int r = 0; r < 4; ++r)
                v[r] = fmaxf(fmaf(acc[m][nt][r], scale[r], shift[r]), 0.0f);
            u32x2 hv;
            hv[0] = pk2(v[0], v[1]);
            hv[1] = pk2(v[2], v[3]);
            const int base = ((mt >> 1) * 4 + nt) * 512
                           + (l15 + 16 * ((mt & 1) * 2 + (l4 >> 1))) * 8
                           + (l4 & 1) * 4;
            *reinterpret_cast<u32x2*>(&HF[base]) = hv;
        }
    }
    __syncthreads();

    // ---- L2: acc2[m2][nt], wave owns mt2 {2w, 2w+1}, K=256 ----
    f32x4 acc2[2][4];
    #pragma unroll
    for (int m2 = 0; m2 < 2; ++m2)
        #pragma unroll
        for (int nt = 0; nt < 4; ++nt) acc2[m2][nt] = (f32x4){0.f, 0.f, 0.f, 0.f};

    #pragma unroll
    for (int ks2 = 0; ks2 < 8; ++ks2) {
        bf16x8 wh2[2], wl2[2];
        #pragma unroll
        for (int m2 = 0; m2 < 2; ++m2) {
            const size_t bo = ((size_t)((w * 2 + m2) * 8 + ks2) * 64 + l) * 8;
            wh2[m2] = *reinterpret_cast<const bf16x8*>(&w2nh[bo]);
            wl2[m2] = *reinterpret_cast<const bf16x8*>(&w2nl[bo]);
        }
        bf16x8 fh[4];
        #pragma unroll
        for (int nt = 0; nt < 4; ++nt)
            fh[nt] = *reinterpret_cast<const bf16x8*>(&HF[(ks2 * 4 + nt) * 512 + l * 8]);
        __builtin_amdgcn_s_setprio(1);
        #pragma unroll
        for (int m2 = 0; m2 < 2; ++m2)
            #pragma unroll
            for (int nt = 0; nt < 4; ++nt)
                acc2[m2][nt] = __builtin_amdgcn_mfma_f32_16x16x32_bf16(wh2[m2], fh[nt], acc2[m2][nt], 0, 0, 0);
        #pragma unroll
        for (int m2 = 0; m2 < 2; ++m2)
            #pragma unroll
            for (int nt = 0; nt < 4; ++nt)
                acc2[m2][nt] = __builtin_amdgcn_mfma_f32_16x16x32_bf16(wl2[m2], fh[nt], acc2[m2][nt], 0, 0, 0);
        __builtin_amdgcn_s_setprio(0);
    }

    // ---- epilogue 2: z = bf16(relu(acc2 + b2)) -> global ----
    #pragma unroll
    for (int m2 = 0; m2 < 2; ++m2) {
        const int nb2 = (w * 2 + m2) * 16 + l4 * 4;
        float4 b2v = *reinterpret_cast<const float4*>(b2 + nb2);
        float bb[4] = {b2v.x, b2v.y, b2v.z, b2v.w};
        #pragma unroll
        for (int nt = 0; nt < 4; ++nt) {
            const int node = n0 + nt * 16 + l15;
            if (node < N_NODES) {
                float v0 = fmaxf(acc2[m2][nt][0] + bb[0], 0.0f);
                float v1 = fmaxf(acc2[m2][nt][1] + bb[1], 0.0f);
                float v2 = fmaxf(acc2[m2][nt][2] + bb[2], 0.0f);
                float v3 = fmaxf(acc2[m2][nt][3] + bb[3], 0.0f);
                u32x2 hv;
                hv[0] = pk2(v0, v1);
                hv[1] = pk2(v2, v3);
                *reinterpret_cast<u32x2*>(z + (size_t)node * EMB + nb2) = hv;
            }
        }
    }
}

// ---------------------------------------------------------------------------
// Kernel B (MFMA): r17 structure with (1) bar3+bar4 merged (epi1 F0+F1 back
// to back, one barrier, then both mfma2 chunks in a single merged loop with
// weight dbuf spanning the old barrier boundary), (2) first-pass L1 weights
// hoisted above bar1, (3) L2 first-chunk weights preloaded before the s1
// barrier. 4 barriers total. Math bit-identical to r15/r17.
// ---------------------------------------------------------------------------
__global__ __launch_bounds__(256) void pair_mfma_kernel(
    const u16* __restrict__ z,
    const int* __restrict__ pairs,
    const float* __restrict__ logdeg,
    const u16* __restrict__ w1h,
    const u16* __restrict__ w2h,
    const float* __restrict__ SW1, const float* __restrict__ Sb1,
    const float* __restrict__ Sb2,
    const float* __restrict__ SW3, const float* __restrict__ Sb3,
    float* __restrict__ out)
{
    __shared__ __align__(16) u16 F0[8192];   // sd  ch0:64   (ks 0,1,4,5)
    __shared__ __align__(16) u16 F1[8192];   // sd  ch64:128 (ks 2,3,6,7)
    __shared__ __align__(16) u16 F2[8192];   // p|ad ch0:64  (ks 8,9,12,13)
    __shared__ __align__(16) u16 F3[8192];   // p|ad ch64:128(ks 10,11,14,15)
    __shared__ float red[4][4][16];          // 1 KB

    const int t   = threadIdx.x;
    const int w   = t >> 6;        // wave 0..3
    const int l   = t & 63;
    const int l15 = l & 15;
    const int l4  = l >> 4;
    const int p0  = blockIdx.x * PBM;

    // thread (w,l): pair l, channels [w*16, w*16+16) of a 64-ch half.
    const int qb  = (w & 1) * 2;
    const int bS0 = (((w >> 1)) * 4 + l4) * 512 + (l15 + 16 * (qb + 0)) * 8;
    const int bS1 = (((w >> 1)) * 4 + l4) * 512 + (l15 + 16 * (qb + 1)) * 8;
    const int bD0 = ((2 + (w >> 1)) * 4 + l4) * 512 + (l15 + 16 * (qb + 0)) * 8;
    const int bD1 = ((2 + (w >> 1)) * 4 + l4) * 512 + (l15 + 16 * (qb + 1)) * 8;

    const int gp  = (p0 + l < N_PAIRS) ? (p0 + l) : (N_PAIRS - 1);
    const int gsi = pairs[(size_t)gp * 2 + 0];
    const int gdi = pairs[(size_t)gp * 2 + 1];

    // ---- gather both halves (bf16, raw u16x8) ----
    const u16* zs0 = z + (size_t)gsi * EMB + w * 16;
    const u16* zd0 = z + (size_t)gdi * EMB + w * 16;
    u16x8 s00 = *reinterpret_cast<const u16x8*>(zs0);
    u16x8 s01 = *reinterpret_cast<const u16x8*>(zs0 + 8);
    u16x8 d00 = *reinterpret_cast<const u16x8*>(zd0);
    u16x8 d01 = *reinterpret_cast<const u16x8*>(zd0 + 8);
    u16x8 s10 = *reinterpret_cast<const u16x8*>(zs0 + 64);
    u16x8 s11 = *reinterpret_cast<const u16x8*>(zs0 + 72);
    u16x8 d10 = *reinterpret_cast<const u16x8*>(zd0 + 64);
    u16x8 d11 = *reinterpret_cast<const u16x8*>(zd0 + 72);

    // rebuild p = s~*d~, ad = |s~-d~| from held registers
    auto rebuildR = [&](u16x8 sa, u16x8 sb, u16x8 da, u16x8 db, float* pv, float* av) {
        #pragma unroll
        for (int qq = 0; qq < 8; ++qq) {
            const float s = bf2f(sa[qq]);
            const float d = bf2f(da[qq]);
            pv[qq] = s * d;
            av[qq] = fabsf(s - d);
        }
        #pragma unroll
        for (int qq = 0; qq < 8; ++qq) {
            const float s = bf2f(sb[qq]);
            const float d = bf2f(db[qq]);
            pv[8 + qq] = s * d;
            av[8 + qq] = fabsf(s - d);
        }
    };

    // ---- stage ALL FOUR segments up-front ----
    *reinterpret_cast<u16x8*>(&F0[bS0]) = s00;
    *reinterpret_cast<u16x8*>(&F0[bS1]) = s01;
    *reinterpret_cast<u16x8*>(&F0[bD0]) = d00;
    *reinterpret_cast<u16x8*>(&F0[bD1]) = d01;
    *reinterpret_cast<u16x8*>(&F1[bS0]) = s10;
    *reinterpret_cast<u16x8*>(&F1[bS1]) = s11;
    *reinterpret_cast<u16x8*>(&F1[bD0]) = d10;
    *reinterpret_cast<u16x8*>(&F1[bD1]) = d11;
    {
        float pv[16], av[16];
        rebuildR(s00, s01, d00, d01, pv, av);
        store8(F2, bS0, pv + 0);
        store8(F2, bS1, pv + 8);
        store8(F2, bD0, av + 0);
        store8(F2, bD1, av + 8);
        rebuildR(s10, s11, d10, d11, pv, av);
        store8(F3, bS0, pv + 0);
        store8(F3, bS1, pv + 8);
        store8(F3, bD0, av + 0);
        store8(F3, bD1, av + 8);
    }

    // ---- prefetch epilogue-1 gather data ----
    float ldS[4], ldD[4];
    #pragma unroll
    for (int nt = 0; nt < 4; ++nt) {
        const int pidx = (p0 + nt * 16 + l15 < N_PAIRS) ? (p0 + nt * 16 + l15) : (N_PAIRS - 1);
        ldS[nt] = logdeg[pairs[(size_t)pidx * 2 + 0]];
        ldD[nt] = logdeg[pairs[(size_t)pidx * 2 + 1]];
    }

    // ---- hoist first-pass (F0, ks=0) weight loads above bar1 ----
    bf16x8 wpre[4];
    #pragma unroll
    for (int m = 0; m < 4; ++m) {
        const size_t bo = ((size_t)((w * 4 + m) * 16 + 0) * 64 + l) * 8;
        wpre[m] = *reinterpret_cast<const bf16x8*>(&w1h[bo]);
    }

    __syncthreads();   // bar1: all features staged

    f32x4 acc[4][4];
    #pragma unroll
    for (int m = 0; m < 4; ++m)
        #pragma unroll
        for (int nt = 0; nt < 4; ++nt) acc[m][nt] = (f32x4){0.f, 0.f, 0.f, 0.f};

    // one 128-K segment; weight dbuf across sl AND feature dbuf across steps;
    // first-step weights supplied by caller (w0) so they can be hoisted.
    auto run_pass = [&](const u16* buf, int k0, int k1, int k2, int k3, const bf16x8* w0) {
        const int ksg[4] = {k0, k1, k2, k3};
        bf16x8 wh[2][4];
        #pragma unroll
        for (int m = 0; m < 4; ++m) wh[0][m] = w0[m];
        bf16x8 fh[2][2];
        #pragma unroll
        for (int e = 0; e < 2; ++e)
            fh[0][e] = *reinterpret_cast<const bf16x8*>(&buf[(e) * 512 + l * 8]);

        #pragma unroll
        for (int st = 0; st < 8; ++st) {
            const int sl   = st >> 1;
            const int nh   = st & 1;
            const int fcur = st & 1;
            const int wcur = sl & 1;
            if (nh == 0 && sl < 3) {
                #pragma unroll
                for (int m = 0; m < 4; ++m) {
                    const size_t bo = ((size_t)((w * 4 + m) * 16 + ksg[sl + 1]) * 64 + l) * 8;
                    wh[wcur ^ 1][m] = *reinterpret_cast<const bf16x8*>(&w1h[bo]);
                }
            }
            if (st < 7) {
                const int nsl = (st + 1) >> 1;
                const int nnh = (st + 1) & 1;
                #pragma unroll
                for (int e = 0; e < 2; ++e)
                    fh[fcur ^ 1][e] = *reinterpret_cast<const bf16x8*>(&buf[(nsl * 4 + nnh * 2 + e) * 512 + l * 8]);
            }
            __builtin_amdgcn_s_setprio(1);
            #pragma unroll
            for (int m = 0; m < 4; ++m)
                #pragma unroll
                for (int e = 0; e < 2; ++e)
                    acc[m][nh * 2 + e] = __builtin_amdgcn_mfma_f32_16x16x32_bf16(wh[wcur][m], fh[fcur][e], acc[m][nh * 2 + e], 0, 0, 0);
            __builtin_amdgcn_s_setprio(0);
        }
    };

    // ---- layer 1: four uninterrupted passes ----
    bf16x8 wnext[4];
    run_pass(F0, 0, 1, 4, 5, wpre);
    #pragma unroll
    for (int m = 0; m < 4; ++m)
        wnext[m] = *reinterpret_cast<const bf16x8*>(&w1h[((size_t)((w * 4 + m) * 16 + 8) * 64 + l) * 8]);
    run_pass(F2, 8, 9, 12, 13, wnext);
    #pragma unroll
    for (int m = 0; m < 4; ++m)
        wnext[m] = *reinterpret_cast<const bf16x8*>(&w1h[((size_t)((w * 4 + m) * 16 + 2) * 64 + l) * 8]);
    run_pass(F1, 2, 3, 6, 7, wnext);
    #pragma unroll
    for (int m = 0; m < 4; ++m)
        wnext[m] = *reinterpret_cast<const bf16x8*>(&w1h[((size_t)((w * 4 + m) * 16 + 10) * 64 + l) * 8]);
    run_pass(F3, 10, 11, 14, 15, wnext);
    __syncthreads();   // bar2: L1 done; F0/F1 reusable

    // ---- layer 2: epi1(F0)+epi1(F1), ONE barrier, merged 8-chunk MFMA loop ----
    f32x4 acc2[2][4];
    #pragma unroll
    for (int m2 = 0; m2 < 2; ++m2)
        #pragma unroll
        for (int nt = 0; nt < 4; ++nt) acc2[m2][nt] = (f32x4){0.f, 0.f, 0.f, 0.f};

    auto epi1 = [&](u16* buf, int g) {
        #pragma unroll
        for (int mm = 0; mm < 2; ++mm) {
            const int m  = 2 * g + mm;
            const int mt = w * 4 + m;
            const int nb = mt * 16 + l4 * 4;
            float sb[4], wa[4], wb[4];
            *reinterpret_cast<float4*>(sb) = *reinterpret_cast<const float4*>(&Sb1[nb]);
            *reinterpret_cast<float4*>(wa) = *reinterpret_cast<const float4*>(&SW1[(size_t)512 * HID + nb]);
            *reinterpret_cast<float4*>(wb) = *reinterpret_cast<const float4*>(&SW1[(size_t)513 * HID + nb]);
            #pragma unroll
            for (int nt = 0; nt < 4; ++nt) {
                float v[4];
                #pragma unroll
                for (int r = 0; r < 4; ++r) {
                    float x0 = acc[m][nt][r] + sb[r];
                    x0 = fmaf(ldS[nt], wa[r], x0);
                    x0 = fmaf(ldD[nt], wb[r], x0);
                    v[r] = fmaxf(x0, 0.0f);
                }
                u32x2 hv;
                hv[0] = pk2(v[0], v[1]);
                hv[1] = pk2(v[2], v[3]);
                const int base = (w * 4 + nt) * 512
                               + (l15 + 16 * ((m & 1) * 2 + (l4 >> 1))) * 8
                               + (l4 & 1) * 4;
                *reinterpret_cast<u32x2*>(&buf[base]) = hv;
            }
        }
    };

    epi1(F0, 0);
    epi1(F1, 1);

    // preload L2 weights for first chunk (i=0: F0, ks2=0) before the barrier
    bf16x8 wh2buf[2][2];
    #pragma unroll
    for (int m2 = 0; m2 < 2; ++m2) {
        const size_t bo = ((size_t)((w * 2 + m2) * 8 + 0) * 64 + l) * 8;
        wh2buf[0][m2] = *reinterpret_cast<const bf16x8*>(&w2h[bo]);
    }

    __syncthreads();   // bar3: all s1 frags visible

    // merged chunk loop: i 0..3 -> F0 (ks2 = 2i), i 4..7 -> F1 (ks2 = 2(i-4)+1)
    #pragma unroll
    for (int i = 0; i < 8; ++i) {
        const int cur = i & 1;
        if (i < 7) {
            const int ni   = i + 1;
            const int nks2 = (ni < 4) ? (ni * 2) : ((ni - 4) * 2 + 1);
            #pragma unroll
            for (int m2 = 0; m2 < 2; ++m2) {
                const size_t bo = ((size_t)((w * 2 + m2) * 8 + nks2) * 64 + l) * 8;
                wh2buf[cur ^ 1][m2] = *reinterpret_cast<const bf16x8*>(&w2h[bo]);
            }
        }
        const u16* buf = (i < 4) ? F0 : F1;
        const int  cs  = i & 3;
        #pragma unroll
        for (int nh = 0; nh < 2; ++nh) {
            bf16x8 fh[2];
            #pragma unroll
            for (int e = 0; e < 2; ++e)
                fh[e] = *reinterpret_cast<const bf16x8*>(&buf[(cs * 4 + nh * 2 + e) * 512 + l * 8]);
            __builtin_amdgcn_s_setprio(1);
            #pragma unroll
            for (int m2 = 0; m2 < 2; ++m2)
                #pragma unroll
                for (int e = 0; e < 2; ++e)
                    acc2[m2][nh * 2 + e] = __builtin_amdgcn_mfma_f32_16x16x32_bf16(wh2buf[cur][m2], fh[e], acc2[m2][nh * 2 + e], 0, 0, 0);
            __builtin_amdgcn_s_setprio(0);
        }
    }

    // ---- epilogue 2 + layer 3 ----
    {
        float part[4] = {0.f, 0.f, 0.f, 0.f};
        #pragma unroll
        for (int m2 = 0; m2 < 2; ++m2) {
            const int nb2 = (w * 2 + m2) * 16 + l4 * 4;
            float sb[4], w3[4];
            *reinterpret_cast<float4*>(sb) = *reinterpret_cast<const float4*>(&Sb2[nb2]);
            *reinterpret_cast<float4*>(w3) = *reinterpret_cast<const float4*>(&SW3[nb2]);
            #pragma unroll
            for (int nt = 0; nt < 4; ++nt)
                #pragma unroll
                for (int r = 0; r < 4; ++r)
                    part[nt] = fmaf(fmaxf(acc2[m2][nt][r] + sb[r], 0.0f), w3[r], part[nt]);
        }
        #pragma unroll
        for (int nt = 0; nt < 4; ++nt) {
            part[nt] += __shfl_xor(part[nt], 16);
            part[nt] += __shfl_xor(part[nt], 32);
        }
        if (l < 16) {
            #pragma unroll
            for (int nt = 0; nt < 4; ++nt) red[w][nt][l15] = part[nt];
        }
    }
    __syncthreads();   // bar4

    if (t < 64) {
        const int nt = t >> 4, pp = t & 15;
        float v = red[0][nt][pp] + red[1][nt][pp] + red[2][nt][pp] + red[3][nt][pp] + Sb3[0];
        if (isnan(v)) v = 0.0f;
        else if (isinf(v)) v = (v > 0.0f) ? 20.0f : -20.0f;
        const int pidx = p0 + nt * 16 + pp;
        if (pidx < N_PAIRS) out[pidx] = v;
    }
}

// ---------------------------------------------------------------------------
extern "C" void kernel_launch(void* const* d_in, const int* in_sizes, int n_in,
                              void* d_out, int out_size, void* d_ws, size_t ws_size,
                              hipStream_t stream)
{
    const float* x        = (const float*)d_in[0];
    // d_in[1] = edge_index : unused by the reference
    const int*   pairs    = (const int*)d_in[2];
    const float* x_mean   = (const float*)d_in[3];
    const float* x_std    = (const float*)d_in[4];
    const float* logdeg   = (const float*)d_in[5];
    const float* W1       = (const float*)d_in[6];
    const float* b1       = (const float*)d_in[7];
    const float* bn_gamma = (const float*)d_in[8];
    const float* bn_beta  = (const float*)d_in[9];
    const float* bn_mean  = (const float*)d_in[10];
    const float* bn_var   = (const float*)d_in[11];
    const float* W2       = (const float*)d_in[12];
    const float* b2       = (const float*)d_in[13];
    const float* SW1      = (const float*)d_in[14];
    const float* Sb1      = (const float*)d_in[15];
    const float* SW2      = (const float*)d_in[16];
    const float* Sb2      = (const float*)d_in[17];
    const float* SW3      = (const float*)d_in[18];
    const float* Sb3      = (const float*)d_in[19];

    float* outp = (float*)d_out;

    // ws layout (z bf16: 25,600,000 B)
    char* wsb = (char*)d_ws;
    u16* zbuf = (u16*)wsb;
    u16* w1h  = (u16*)(wsb + 25600000);                 // 262144 B
    u16* w2h  = (u16*)(wsb + 25862144);                 // 65536 B
    u16* w1nh = (u16*)(wsb + 25927680);                 // 65536 B
    u16* w1nl = (u16*)(wsb + 25993216);                 // 65536 B
    u16* w2nh = (u16*)(wsb + 26058752);                 // 65536 B
    u16* w2nl = (u16*)(wsb + 26124288);                 // 65536 B (end 26,189,824)

    prep_weights<<<896, 256, 0, stream>>>(SW1, SW2, W1, W2,
                                          w1h, w2h,
                                          w1nh, w1nl, w2nh, w2nl);

    node_mfma_kernel<<<(N_NODES + 63) / 64, 256, 0, stream>>>(
        x, x_mean, x_std, b1, bn_gamma, bn_beta, bn_mean, bn_var, b2,
        w1nh, w1nl, w2nh, w2nl, zbuf);

    pair_mfma_kernel<<<(N_PAIRS + PBM - 1) / PBM, 256, 0, stream>>>(
        zbuf, pairs, logdeg, w1h, w2h, SW1, Sb1, Sb2, SW3, Sb3, outp);
}